// Round 1
// baseline (30282.480 us; speedup 1.0000x reference)
//
#include <hip/hip_runtime.h>
#include <hip/hip_bf16.h>
#include <cstdint>

#define TB 16
#define TT 16384
#define TI 64
#define TH 128
#define TG 512  // 4*H

__device__ __forceinline__ float sigf(float z) {
    return 1.0f / (1.0f + __expf(-z));
}
__device__ __forceinline__ float tanhf_fast(float z) {
    // 2*sigmoid(2z)-1 ; saturates correctly via inf arithmetic
    return 2.0f / (1.0f + __expf(-2.0f * z)) - 1.0f;
}
__device__ __forceinline__ float4 ld4(const float* p) {
    return *reinterpret_cast<const float4*>(p);
}
__device__ __forceinline__ void fma4(float4& acc, const float4 w, const float4 h) {
    acc.x = fmaf(w.x, h.x, acc.x);
    acc.y = fmaf(w.y, h.y, acc.y);
    acc.z = fmaf(w.z, h.z, acc.z);
    acc.w = fmaf(w.w, h.w, acc.w);
}
__device__ __forceinline__ float hsum4(const float4 a) {
    return (a.x + a.y) + (a.z + a.w);
}

// ---------------------------------------------------------------------------
// gx = x @ W_ih^T + b_ih + b_hh   (only used when d_ws is big enough)
// grid 2048 x 256 threads; each block handles 128 rows; thread owns 2 W rows.
// ---------------------------------------------------------------------------
__global__ __launch_bounds__(256, 2) void gx_precompute(
    const float* __restrict__ x, const float* __restrict__ W_ih,
    const float* __restrict__ b_ih, const float* __restrict__ b_hh,
    float* __restrict__ gx)
{
    const int tid  = threadIdx.x;
    const int j    = tid & (TH - 1);
    const int pair = tid >> 7;
    const int row_a = pair * 2 * TH + j;   // i (0..127) or g (256..383)
    const int row_b = row_a + TH;          // f or o

    float4 ua[TI / 4], ub[TI / 4];
#pragma unroll
    for (int k4 = 0; k4 < TI / 4; ++k4) {
        ua[k4] = ld4(W_ih + (size_t)row_a * TI + k4 * 4);
        ub[k4] = ld4(W_ih + (size_t)row_b * TI + k4 * 4);
    }
    const float bias_a = b_ih[row_a] + b_hh[row_a];
    const float bias_b = b_ih[row_b] + b_hh[row_b];

    __shared__ __align__(16) float xs[2][TI];
    const int ROWS = 128;
    const size_t r0 = (size_t)blockIdx.x * ROWS;

    if (tid < TI / 4)
        *reinterpret_cast<float4*>(&xs[0][tid * 4]) = ld4(x + r0 * TI + tid * 4);
    __syncthreads();
    float4 xreg = make_float4(0.f, 0.f, 0.f, 0.f);
    if (tid < TI / 4) xreg = ld4(x + (r0 + 1) * TI + tid * 4);

#pragma unroll 1
    for (int rr = 0; rr < ROWS; ++rr) {
        const float* xrow = xs[rr & 1];
        float4 aa = make_float4(0.f, 0.f, 0.f, 0.f);
        float4 ab = make_float4(0.f, 0.f, 0.f, 0.f);
#pragma unroll
        for (int k4 = 0; k4 < TI / 4; ++k4) {
            const float4 x4 = *reinterpret_cast<const float4*>(&xrow[k4 * 4]);
            fma4(aa, ua[k4], x4);
            fma4(ab, ub[k4], x4);
        }
        // stage next x row (target buffer was last read at rr-1; safe)
        if (tid < TI / 4) {
            if (rr + 1 < ROWS)
                *reinterpret_cast<float4*>(&xs[(rr + 1) & 1][tid * 4]) = xreg;
            if (rr + 2 < ROWS) xreg = ld4(x + (r0 + rr + 2) * TI + tid * 4);
        }
        float* grow = gx + (r0 + rr) * (size_t)TG;
        grow[row_a] = hsum4(aa) + bias_a;
        grow[row_b] = hsum4(ab) + bias_b;

        asm volatile("s_waitcnt lgkmcnt(0)" ::: "memory");
        __builtin_amdgcn_s_barrier();
    }
}

// ---------------------------------------------------------------------------
// Sequential LSTM scan. One block per batch element. 256 threads.
// pair 0 (tid<128): gate rows (i, f) ; pair 1: gate rows (g, o).
// FUSED=1: also computes x @ W_ih^T on the fly (no gx buffer needed).
// ---------------------------------------------------------------------------
template <int FUSED>
__global__ __launch_bounds__(256, 1) void lstm_scan(
    const float* __restrict__ x, const float* __restrict__ W_ih,
    const float* __restrict__ W_hh, const float* __restrict__ b_ih,
    const float* __restrict__ b_hh, const float* __restrict__ gx,
    float* __restrict__ y, float* __restrict__ hn, float* __restrict__ cn)
{
    const int b    = blockIdx.x;
    const int tid  = threadIdx.x;
    const int j    = tid & (TH - 1);
    const int pair = tid >> 7;
    const int row_a = pair * 2 * TH + j;
    const int row_b = row_a + TH;

    __shared__ __align__(16) float  h_lds[TH];
    __shared__ __align__(16) float2 ex[TH];      // (tanh(g), sig(o))
    __shared__ __align__(16) float  xs[2][TI];   // FUSED only

    // recurrent weights in registers: 2 rows x 128 f32 = 256 VGPR
    float4 wa[TH / 4], wb[TH / 4];
#pragma unroll
    for (int k4 = 0; k4 < TH / 4; ++k4) {
        wa[k4] = ld4(W_hh + (size_t)row_a * TH + k4 * 4);
        wb[k4] = ld4(W_hh + (size_t)row_b * TH + k4 * 4);
    }
    float4 ua[TI / 4], ub[TI / 4];
    float bias_a = 0.f, bias_b = 0.f;
    if (FUSED) {
#pragma unroll
        for (int k4 = 0; k4 < TI / 4; ++k4) {
            ua[k4] = ld4(W_ih + (size_t)row_a * TI + k4 * 4);
            ub[k4] = ld4(W_ih + (size_t)row_b * TI + k4 * 4);
        }
        bias_a = b_ih[row_a] + b_hh[row_a];
        bias_b = b_ih[row_b] + b_hh[row_b];
    }

    if (tid < TH) h_lds[tid] = 0.0f;
    float c_state = 0.0f;
    float h_keep  = 0.0f;

    // prefetch setup
    float  ga_c = 0.f, gb_c = 0.f, ga_n = 0.f, gb_n = 0.f;
    float4 xreg = make_float4(0.f, 0.f, 0.f, 0.f);
    const float* gp = gx ? (gx + ((size_t)b * TT + 2) * TG) : nullptr;
    const float* xp = x + ((size_t)b * TT + 2) * TI;
    float* yp = y + (size_t)b * TT * TH;

    if (FUSED) {
        if (tid < TI / 4)
            *reinterpret_cast<float4*>(&xs[0][tid * 4]) =
                ld4(x + ((size_t)b * TT + 0) * TI + tid * 4);
    } else {
        const float* g0 = gx + ((size_t)b * TT) * TG;
        ga_c = g0[row_a];      gb_c = g0[row_b];
        ga_n = g0[TG + row_a]; gb_n = g0[TG + row_b];
    }
    __syncthreads();
    if (FUSED && tid < TI / 4)
        xreg = ld4(x + ((size_t)b * TT + 1) * TI + tid * 4);

#pragma unroll 1
    for (int t = 0; t < TT; ++t) {
        // ---- gate pre-activations: h . W_hh rows ----
        float4 aa = make_float4(0.f, 0.f, 0.f, 0.f);
        float4 ab = make_float4(0.f, 0.f, 0.f, 0.f);
#pragma unroll
        for (int k4 = 0; k4 < TH / 4; ++k4) {
            const float4 h4 = *reinterpret_cast<const float4*>(&h_lds[k4 * 4]);
            fma4(aa, wa[k4], h4);
            fma4(ab, wb[k4], h4);
        }
        float pa = hsum4(aa);
        float pb = hsum4(ab);
        if (FUSED) {
            float4 fa = make_float4(0.f, 0.f, 0.f, 0.f);
            float4 fb = make_float4(0.f, 0.f, 0.f, 0.f);
            const float* xrow = xs[t & 1];
#pragma unroll
            for (int k4 = 0; k4 < TI / 4; ++k4) {
                const float4 x4 = *reinterpret_cast<const float4*>(&xrow[k4 * 4]);
                fma4(fa, ua[k4], x4);
                fma4(fb, ub[k4], x4);
            }
            pa += hsum4(fa) + bias_a;
            pb += hsum4(fb) + bias_b;
        } else {
            pa += ga_c;
            pb += gb_c;
        }

        // ---- activations ----
        if (pair == 0) {
            pa = sigf(pa);   // i
            pb = sigf(pb);   // f
        } else {
            ex[j] = make_float2(tanhf_fast(pa), sigf(pb));  // (g, o)
        }

        asm volatile("s_waitcnt lgkmcnt(0)" ::: "memory");
        __builtin_amdgcn_s_barrier();

        // ---- state update (pair 0 only) ----
        if (pair == 0) {
            const float2 go = ex[j];
            c_state = fmaf(pb, c_state, pa * go.x);
            h_keep  = go.y * tanhf_fast(c_state);
            h_lds[j] = h_keep;
            yp[(size_t)t * TH + j] = h_keep;
        }

        // ---- prefetch for t+2 ----
        if (FUSED) {
            if (tid < TI / 4) {
                if (t + 1 < TT)
                    *reinterpret_cast<float4*>(&xs[(t + 1) & 1][tid * 4]) = xreg;
                if (t + 2 < TT) { xreg = ld4(xp + tid * 4); }
            }
            xp += TI;
        } else {
            ga_c = ga_n; gb_c = gb_n;
            if (t + 2 < TT) {
                ga_n = gp[row_a];
                gb_n = gp[row_b];
                gp += TG;
            }
        }

        asm volatile("s_waitcnt lgkmcnt(0)" ::: "memory");
        __builtin_amdgcn_s_barrier();
    }

    if (pair == 0) {
        hn[(size_t)b * TH + j] = h_keep;
        cn[(size_t)b * TH + j] = c_state;
    }
}

// ---------------------------------------------------------------------------
// BatchNorm over flattened [B*T, H] + LeakyReLU
// ---------------------------------------------------------------------------
__global__ void bn_zero(float* ws) { ws[threadIdx.x] = 0.0f; }

__global__ __launch_bounds__(256) void bn_stats(const float* __restrict__ y,
                                                float* __restrict__ ws)
{
    const int tid  = threadIdx.x;
    const int col4 = tid & 31;   // which float4 within the 128-channel row
    const int rg   = tid >> 5;   // 8 row groups
    const int NROW = TB * TT;
    float4 s = make_float4(0.f, 0.f, 0.f, 0.f);
    float4 q = make_float4(0.f, 0.f, 0.f, 0.f);
    for (int row = blockIdx.x * 8 + rg; row < NROW; row += gridDim.x * 8) {
        const float4 v = ld4(y + (size_t)row * TH + col4 * 4);
        s.x += v.x; s.y += v.y; s.z += v.z; s.w += v.w;
        q.x = fmaf(v.x, v.x, q.x); q.y = fmaf(v.y, v.y, q.y);
        q.z = fmaf(v.z, v.z, q.z); q.w = fmaf(v.w, v.w, q.w);
    }
    __shared__ float4 ls[256], lq[256];
    ls[tid] = s; lq[tid] = q;
    __syncthreads();
    if (tid < 32) {
        float4 S = ls[tid], Q = lq[tid];
        for (int g2 = 1; g2 < 8; ++g2) {
            const float4 a = ls[g2 * 32 + tid], b2 = lq[g2 * 32 + tid];
            S.x += a.x; S.y += a.y; S.z += a.z; S.w += a.w;
            Q.x += b2.x; Q.y += b2.y; Q.z += b2.z; Q.w += b2.w;
        }
        atomicAdd(&ws[tid * 4 + 0], S.x); atomicAdd(&ws[tid * 4 + 1], S.y);
        atomicAdd(&ws[tid * 4 + 2], S.z); atomicAdd(&ws[tid * 4 + 3], S.w);
        atomicAdd(&ws[TH + tid * 4 + 0], Q.x); atomicAdd(&ws[TH + tid * 4 + 1], Q.y);
        atomicAdd(&ws[TH + tid * 4 + 2], Q.z); atomicAdd(&ws[TH + tid * 4 + 3], Q.w);
    }
}

__global__ __launch_bounds__(256) void bn_apply(float* __restrict__ y,
                                                const float* __restrict__ ws,
                                                const float* __restrict__ gamma,
                                                const float* __restrict__ beta)
{
    const int tid  = threadIdx.x;
    const int col4 = tid & 31;
    const int rg   = tid >> 5;
    const int NROW = TB * TT;
    const float invN = 1.0f / (float)(TB * TT);

    const float4 sm = ld4(ws + col4 * 4);
    const float4 sq = ld4(ws + TH + col4 * 4);
    const float4 gm = ld4(gamma + col4 * 4);
    const float4 bt = ld4(beta + col4 * 4);
    float4 mean, scale, shift;
    mean.x = sm.x * invN; mean.y = sm.y * invN;
    mean.z = sm.z * invN; mean.w = sm.w * invN;
    scale.x = rsqrtf(fmaf(-mean.x, mean.x, sq.x * invN) + 1e-5f) * gm.x;
    scale.y = rsqrtf(fmaf(-mean.y, mean.y, sq.y * invN) + 1e-5f) * gm.y;
    scale.z = rsqrtf(fmaf(-mean.z, mean.z, sq.z * invN) + 1e-5f) * gm.z;
    scale.w = rsqrtf(fmaf(-mean.w, mean.w, sq.w * invN) + 1e-5f) * gm.w;
    shift.x = bt.x - mean.x * scale.x; shift.y = bt.y - mean.y * scale.y;
    shift.z = bt.z - mean.z * scale.z; shift.w = bt.w - mean.w * scale.w;

    for (int row = blockIdx.x * 8 + rg; row < NROW; row += gridDim.x * 8) {
        float* p = y + (size_t)row * TH + col4 * 4;
        float4 v = *reinterpret_cast<const float4*>(p);
        v.x = fmaf(v.x, scale.x, shift.x); v.y = fmaf(v.y, scale.y, shift.y);
        v.z = fmaf(v.z, scale.z, shift.z); v.w = fmaf(v.w, scale.w, shift.w);
        v.x = fmaxf(v.x, 0.01f * v.x); v.y = fmaxf(v.y, 0.01f * v.y);
        v.z = fmaxf(v.z, 0.01f * v.z); v.w = fmaxf(v.w, 0.01f * v.w);
        *reinterpret_cast<float4*>(p) = v;
    }
}

// ---------------------------------------------------------------------------
extern "C" void kernel_launch(void* const* d_in, const int* in_sizes, int n_in,
                              void* d_out, int out_size, void* d_ws, size_t ws_size,
                              hipStream_t stream)
{
    const float* x     = (const float*)d_in[0];
    const float* W_ih  = (const float*)d_in[1];
    const float* W_hh  = (const float*)d_in[2];
    const float* b_ih  = (const float*)d_in[3];
    const float* b_hh  = (const float*)d_in[4];
    const float* gamma = (const float*)d_in[5];
    const float* beta  = (const float*)d_in[6];

    float* y  = (float*)d_out;
    float* hn = y + (size_t)TB * TT * TH;
    float* cn = hn + TB * TH;

    float* ws_stats = (float*)d_ws;
    const size_t GX_BYTES = (size_t)TB * TT * TG * sizeof(float);
    const bool use_ws = ws_size >= GX_BYTES + 4096;

    bn_zero<<<1, 256, 0, stream>>>(ws_stats);

    if (use_ws) {
        float* gxbuf = (float*)((char*)d_ws + 4096);
        gx_precompute<<<2048, 256, 0, stream>>>(x, W_ih, b_ih, b_hh, gxbuf);
        lstm_scan<0><<<TB, 256, 0, stream>>>(x, W_ih, W_hh, b_ih, b_hh, gxbuf,
                                             y, hn, cn);
    } else {
        lstm_scan<1><<<TB, 256, 0, stream>>>(x, W_ih, W_hh, b_ih, b_hh, nullptr,
                                             y, hn, cn);
    }

    bn_stats<<<512, 256, 0, stream>>>(y, ws_stats);
    bn_apply<<<2048, 256, 0, stream>>>(y, ws_stats, gamma, beta);
}

// Round 2
// 19136.163 us; speedup vs baseline: 1.5825x; 1.5825x over previous
//
#include <hip/hip_runtime.h>
#include <hip/hip_bf16.h>
#include <cstdint>

#define TB 16
#define TT 16384
#define TI 64
#define TH 128
#define TG 512  // 4*H

__device__ __forceinline__ float sigf(float z) {
    return 1.0f / (1.0f + __expf(-z));
}
__device__ __forceinline__ float tanhf_fast(float z) {
    return 2.0f / (1.0f + __expf(-2.0f * z)) - 1.0f;
}
__device__ __forceinline__ float4 ld4(const float* p) {
    return *reinterpret_cast<const float4*>(p);
}
__device__ __forceinline__ void fma4(float4& acc, const float4 w, const float4 h) {
    acc.x = fmaf(w.x, h.x, acc.x);
    acc.y = fmaf(w.y, h.y, acc.y);
    acc.z = fmaf(w.z, h.z, acc.z);
    acc.w = fmaf(w.w, h.w, acc.w);
}
__device__ __forceinline__ float hsum4(const float4 a) {
    return (a.x + a.y) + (a.z + a.w);
}

// ---------------------------------------------------------------------------
// gx = x @ W_ih^T + b_ih + b_hh   (only used when d_ws is big enough)
// ---------------------------------------------------------------------------
__global__ __launch_bounds__(256, 2) void gx_precompute(
    const float* __restrict__ x, const float* __restrict__ W_ih,
    const float* __restrict__ b_ih, const float* __restrict__ b_hh,
    float* __restrict__ gx)
{
    const int tid  = threadIdx.x;
    const int j    = tid & (TH - 1);
    const int pair = tid >> 7;
    const int row_a = pair * 2 * TH + j;
    const int row_b = row_a + TH;

    float4 ua[TI / 4], ub[TI / 4];
#pragma unroll
    for (int k4 = 0; k4 < TI / 4; ++k4) {
        ua[k4] = ld4(W_ih + (size_t)row_a * TI + k4 * 4);
        ub[k4] = ld4(W_ih + (size_t)row_b * TI + k4 * 4);
    }
    const float bias_a = b_ih[row_a] + b_hh[row_a];
    const float bias_b = b_ih[row_b] + b_hh[row_b];

    __shared__ __align__(16) float xs[2][TI];
    const int ROWS = 128;
    const size_t r0 = (size_t)blockIdx.x * ROWS;

    if (tid < TI / 4)
        *reinterpret_cast<float4*>(&xs[0][tid * 4]) = ld4(x + r0 * TI + tid * 4);
    __syncthreads();
    float4 xreg = make_float4(0.f, 0.f, 0.f, 0.f);
    if (tid < TI / 4) xreg = ld4(x + (r0 + 1) * TI + tid * 4);

#pragma unroll 1
    for (int rr = 0; rr < ROWS; ++rr) {
        const float* xrow = xs[rr & 1];
        float4 aa = make_float4(0.f, 0.f, 0.f, 0.f);
        float4 ab = make_float4(0.f, 0.f, 0.f, 0.f);
#pragma unroll
        for (int k4 = 0; k4 < TI / 4; ++k4) {
            const float4 x4 = *reinterpret_cast<const float4*>(&xrow[k4 * 4]);
            fma4(aa, ua[k4], x4);
            fma4(ab, ub[k4], x4);
        }
        if (tid < TI / 4) {
            if (rr + 1 < ROWS)
                *reinterpret_cast<float4*>(&xs[(rr + 1) & 1][tid * 4]) = xreg;
            if (rr + 2 < ROWS) xreg = ld4(x + (r0 + rr + 2) * TI + tid * 4);
        }
        float* grow = gx + (r0 + rr) * (size_t)TG;
        grow[row_a] = hsum4(aa) + bias_a;
        grow[row_b] = hsum4(ab) + bias_b;

        asm volatile("s_waitcnt lgkmcnt(0)" ::: "memory");
        __builtin_amdgcn_s_barrier();
    }
}

// ---------------------------------------------------------------------------
// Sequential LSTM scan. One block per batch element. 512 threads.
// Thread tid owns gate row tid (one 128-long dot product -> 128 VGPRs of W).
// gate = tid>>7 : 0=i, 1=f, 2=g, 3=o  (wave-uniform).
// ---------------------------------------------------------------------------
template <int FUSED>
__global__ __launch_bounds__(512, 2) void lstm_scan(
    const float* __restrict__ x, const float* __restrict__ W_ih,
    const float* __restrict__ W_hh, const float* __restrict__ b_ih,
    const float* __restrict__ b_hh, const float* __restrict__ gx,
    float* __restrict__ y, float* __restrict__ hn, float* __restrict__ cn)
{
    const int b    = blockIdx.x;
    const int tid  = threadIdx.x;          // gate row 0..511
    const int j    = tid & (TH - 1);
    const int gate = tid >> 7;             // wave-uniform

    __shared__ __align__(16) float h_lds[TH];
    __shared__ __align__(16) float g_lds[TG];
    __shared__ __align__(16) float xs[2][TI];   // FUSED only

    // one W_hh row in registers: 128 f32 = 32 float4 = 128 VGPRs
    float4 w[TH / 4];
#pragma unroll
    for (int k4 = 0; k4 < TH / 4; ++k4)
        w[k4] = ld4(W_hh + (size_t)tid * TH + k4 * 4);

    float4 u[TI / 4];
    float bias = 0.f;
    if (FUSED) {
#pragma unroll
        for (int k4 = 0; k4 < TI / 4; ++k4)
            u[k4] = ld4(W_ih + (size_t)tid * TI + k4 * 4);
        bias = b_ih[tid] + b_hh[tid];
    }

    if (tid < TH) h_lds[tid] = 0.0f;
    float c_state = 0.0f;
    float h_keep  = 0.0f;

    // gx prefetch (2 steps ahead)
    float  g_c = 0.f, g_n = 0.f;
    float4 xreg = make_float4(0.f, 0.f, 0.f, 0.f);
    const float* gp = gx ? (gx + ((size_t)b * TT + 2) * TG) : nullptr;
    const float* xp = x + ((size_t)b * TT + 2) * TI;
    float* yp = y + (size_t)b * TT * TH;

    if (FUSED) {
        if (tid < TI / 4)
            *reinterpret_cast<float4*>(&xs[0][tid * 4]) =
                ld4(x + ((size_t)b * TT + 0) * TI + tid * 4);
    } else {
        const float* g0 = gx + ((size_t)b * TT) * TG;
        g_c = g0[tid];
        g_n = g0[TG + tid];
    }
    __syncthreads();
    if (FUSED && tid < TI / 4)
        xreg = ld4(x + ((size_t)b * TT + 1) * TI + tid * 4);

#pragma unroll 1
    for (int t = 0; t < TT; ++t) {
        // ---- gate pre-activation: one 128-long dot against LDS-broadcast h
        float4 acc = make_float4(0.f, 0.f, 0.f, 0.f);
#pragma unroll
        for (int k4 = 0; k4 < TH / 4; ++k4) {
            const float4 h4 = *reinterpret_cast<const float4*>(&h_lds[k4 * 4]);
            fma4(acc, w[k4], h4);
        }
        float p = hsum4(acc);
        if (FUSED) {
            float4 fx = make_float4(0.f, 0.f, 0.f, 0.f);
            const float* xrow = xs[t & 1];
#pragma unroll
            for (int k4 = 0; k4 < TI / 4; ++k4) {
                const float4 x4 = *reinterpret_cast<const float4*>(&xrow[k4 * 4]);
                fma4(fx, u[k4], x4);
            }
            p += hsum4(fx) + bias;
        } else {
            p += g_c;
        }

        // ---- activation (gate is wave-uniform; no divergence) ----
        const float act = (gate == 2) ? tanhf_fast(p) : sigf(p);
        g_lds[tid] = act;

        asm volatile("s_waitcnt lgkmcnt(0)" ::: "memory");
        __builtin_amdgcn_s_barrier();

        // ---- state update: threads 0..127 (waves 0,1) ----
        if (tid < TH) {
            const float gi = g_lds[j];
            const float gf = g_lds[TH + j];
            const float gg = g_lds[2 * TH + j];
            const float go = g_lds[3 * TH + j];
            c_state = fmaf(gf, c_state, gi * gg);
            h_keep  = go * tanhf_fast(c_state);
            h_lds[j] = h_keep;
            yp[(size_t)t * TH + j] = h_keep;
        }

        // ---- prefetch for t+2 ----
        if (FUSED) {
            if (tid < TI / 4) {
                if (t + 1 < TT)
                    *reinterpret_cast<float4*>(&xs[(t + 1) & 1][tid * 4]) = xreg;
                if (t + 2 < TT) xreg = ld4(xp + tid * 4);
            }
            xp += TI;
        } else {
            g_c = g_n;
            if (t + 2 < TT) {
                g_n = gp[tid];
                gp += TG;
            }
        }

        asm volatile("s_waitcnt lgkmcnt(0)" ::: "memory");
        __builtin_amdgcn_s_barrier();
    }

    if (tid < TH) {
        hn[(size_t)b * TH + j] = h_keep;
        cn[(size_t)b * TH + j] = c_state;
    }
}

// ---------------------------------------------------------------------------
// BatchNorm over flattened [B*T, H] + LeakyReLU
// ---------------------------------------------------------------------------
__global__ void bn_zero(float* ws) { ws[threadIdx.x] = 0.0f; }

__global__ __launch_bounds__(256) void bn_stats(const float* __restrict__ y,
                                                float* __restrict__ ws)
{
    const int tid  = threadIdx.x;
    const int col4 = tid & 31;
    const int rg   = tid >> 5;
    const int NROW = TB * TT;
    float4 s = make_float4(0.f, 0.f, 0.f, 0.f);
    float4 q = make_float4(0.f, 0.f, 0.f, 0.f);
    for (int row = blockIdx.x * 8 + rg; row < NROW; row += gridDim.x * 8) {
        const float4 v = ld4(y + (size_t)row * TH + col4 * 4);
        s.x += v.x; s.y += v.y; s.z += v.z; s.w += v.w;
        q.x = fmaf(v.x, v.x, q.x); q.y = fmaf(v.y, v.y, q.y);
        q.z = fmaf(v.z, v.z, q.z); q.w = fmaf(v.w, v.w, q.w);
    }
    __shared__ float4 ls[256], lq[256];
    ls[tid] = s; lq[tid] = q;
    __syncthreads();
    if (tid < 32) {
        float4 S = ls[tid], Q = lq[tid];
        for (int g2 = 1; g2 < 8; ++g2) {
            const float4 a = ls[g2 * 32 + tid], b2 = lq[g2 * 32 + tid];
            S.x += a.x; S.y += a.y; S.z += a.z; S.w += a.w;
            Q.x += b2.x; Q.y += b2.y; Q.z += b2.z; Q.w += b2.w;
        }
        atomicAdd(&ws[tid * 4 + 0], S.x); atomicAdd(&ws[tid * 4 + 1], S.y);
        atomicAdd(&ws[tid * 4 + 2], S.z); atomicAdd(&ws[tid * 4 + 3], S.w);
        atomicAdd(&ws[TH + tid * 4 + 0], Q.x); atomicAdd(&ws[TH + tid * 4 + 1], Q.y);
        atomicAdd(&ws[TH + tid * 4 + 2], Q.z); atomicAdd(&ws[TH + tid * 4 + 3], Q.w);
    }
}

__global__ __launch_bounds__(256) void bn_apply(float* __restrict__ y,
                                                const float* __restrict__ ws,
                                                const float* __restrict__ gamma,
                                                const float* __restrict__ beta)
{
    const int tid  = threadIdx.x;
    const int col4 = tid & 31;
    const int rg   = tid >> 5;
    const int NROW = TB * TT;
    const float invN = 1.0f / (float)(TB * TT);

    const float4 sm = ld4(ws + col4 * 4);
    const float4 sq = ld4(ws + TH + col4 * 4);
    const float4 gm = ld4(gamma + col4 * 4);
    const float4 bt = ld4(beta + col4 * 4);
    float4 mean, scale, shift;
    mean.x = sm.x * invN; mean.y = sm.y * invN;
    mean.z = sm.z * invN; mean.w = sm.w * invN;
    scale.x = rsqrtf(fmaf(-mean.x, mean.x, sq.x * invN) + 1e-5f) * gm.x;
    scale.y = rsqrtf(fmaf(-mean.y, mean.y, sq.y * invN) + 1e-5f) * gm.y;
    scale.z = rsqrtf(fmaf(-mean.z, mean.z, sq.z * invN) + 1e-5f) * gm.z;
    scale.w = rsqrtf(fmaf(-mean.w, mean.w, sq.w * invN) + 1e-5f) * gm.w;
    shift.x = bt.x - mean.x * scale.x; shift.y = bt.y - mean.y * scale.y;
    shift.z = bt.z - mean.z * scale.z; shift.w = bt.w - mean.w * scale.w;

    for (int row = blockIdx.x * 8 + rg; row < NROW; row += gridDim.x * 8) {
        float* p = y + (size_t)row * TH + col4 * 4;
        float4 v = *reinterpret_cast<const float4*>(p);
        v.x = fmaf(v.x, scale.x, shift.x); v.y = fmaf(v.y, scale.y, shift.y);
        v.z = fmaf(v.z, scale.z, shift.z); v.w = fmaf(v.w, scale.w, shift.w);
        v.x = fmaxf(v.x, 0.01f * v.x); v.y = fmaxf(v.y, 0.01f * v.y);
        v.z = fmaxf(v.z, 0.01f * v.z); v.w = fmaxf(v.w, 0.01f * v.w);
        *reinterpret_cast<float4*>(p) = v;
    }
}

// ---------------------------------------------------------------------------
extern "C" void kernel_launch(void* const* d_in, const int* in_sizes, int n_in,
                              void* d_out, int out_size, void* d_ws, size_t ws_size,
                              hipStream_t stream)
{
    const float* x     = (const float*)d_in[0];
    const float* W_ih  = (const float*)d_in[1];
    const float* W_hh  = (const float*)d_in[2];
    const float* b_ih  = (const float*)d_in[3];
    const float* b_hh  = (const float*)d_in[4];
    const float* gamma = (const float*)d_in[5];
    const float* beta  = (const float*)d_in[6];

    float* y  = (float*)d_out;
    float* hn = y + (size_t)TB * TT * TH;
    float* cn = hn + TB * TH;

    float* ws_stats = (float*)d_ws;
    const size_t GX_BYTES = (size_t)TB * TT * TG * sizeof(float);
    const bool use_ws = ws_size >= GX_BYTES + 4096;

    bn_zero<<<1, 256, 0, stream>>>(ws_stats);

    if (use_ws) {
        float* gxbuf = (float*)((char*)d_ws + 4096);
        gx_precompute<<<2048, 256, 0, stream>>>(x, W_ih, b_ih, b_hh, gxbuf);
        lstm_scan<0><<<TB, 512, 0, stream>>>(x, W_ih, W_hh, b_ih, b_hh, gxbuf,
                                             y, hn, cn);
    } else {
        lstm_scan<1><<<TB, 512, 0, stream>>>(x, W_ih, W_hh, b_ih, b_hh, nullptr,
                                             y, hn, cn);
    }

    bn_stats<<<512, 256, 0, stream>>>(y, ws_stats);
    bn_apply<<<2048, 256, 0, stream>>>(y, ws_stats, gamma, beta);
}